// Round 1
// baseline (119.967 us; speedup 1.0000x reference)
//
#include <hip/hip_runtime.h>

#define HW 28
#define NPIX 784
#define NB 512
#define PADW2 34                 // row stride in PIXELS (cols -3..30); 136 B, 8B-aligned rows
#define PADH 34                  // rows -3..30
#define IMG_U (PADH * PADW2)     // 1156 packed pixels = 4624 B per branch buffer

// ---------------------------------------------------------------------------
// 7x2 output tile per thread. Image pixels packed fp16x2 (ev lo, pv hi) in
// one uint; weights packed as uint2 { wq = (qw=w*ew lo, ew hi),
//                                     wd = (ew lo, 0 hi) = wq >> 16 }.
// Per tap-output:
//   num += v_dot2_f32_f16(tap, wq)   ( = ev*qw + pv*ew, FULL-rate, 2 cyc )
//   den += v_dot2_f32_f16(tap, wd)   ( = ev*ew + pv*0,  FULL-rate, 2 cyc )
// r17 lesson: fma_mix is HALF-rate (4 cyc) — replacing the den fma_mix with a
// full-rate dot2 against (ew,0) cuts the conv core from 6 to 4 cyc/tap-output.
// asm keeps f16 consumption inside the instruction (nothing for LICM to
// hoist -> no r14-style spill); compiler sinks the weight array to in-loop
// LDS broadcast reads (b64), which ride the idle LDS pipe.
// ---------------------------------------------------------------------------
__device__ __forceinline__ void conv2col(const unsigned* sbuf,
                                         const uint2* wlds,   // LDS packed, 16B-aligned
                                         int R0, int c, float o0[7], float o1[7])
{
    unsigned Wq[49], Wd[49];
    {
        const uint4* wp = (const uint4*)wlds;      // broadcast, conflict-free
#pragma unroll
        for (int k = 0; k < 24; ++k) {
            uint4 q = wp[k];
            Wq[2 * k + 0] = q.x; Wd[2 * k + 0] = q.y;
            Wq[2 * k + 1] = q.z; Wd[2 * k + 1] = q.w;
        }
        Wq[48] = wlds[48].x;
        Wd[48] = wlds[48].y;
    }

    float num0[7], num1[7], den0[7], den1[7];
#pragma unroll
    for (int r = 0; r < 7; ++r) {
        num0[r] = 0.f; num1[r] = 0.f; den0[r] = 0.f; den1[r] = 0.f;
    }

#pragma unroll
    for (int rr = 0; rr < 13; ++rr) {
        const uint2* rq = (const uint2*)(sbuf + (R0 + rr) * PADW2 + 2 * c); // 8B-aligned
        uint2 a0 = rq[0], a1 = rq[1], a2 = rq[2], a3 = rq[3];
        unsigned tp[8] = {a0.x, a0.y, a1.x, a1.y, a2.x, a2.y, a3.x, a3.y};
#pragma unroll
        for (int r = 0; r < 7; ++r) {
            if (r > rr || rr - r > 6) continue;     // compile-time fold
            const int di = rr - r;
#pragma unroll
            for (int t = 0; t < 7; ++t) {
                unsigned wq = Wq[di * 7 + t];
                unsigned wd = Wd[di * 7 + t];
                asm("v_dot2_f32_f16 %0, %1, %2, %0"
                    : "+v"(num0[r]) : "v"(tp[t]),     "v"(wq));
                asm("v_dot2_f32_f16 %0, %1, %2, %0"
                    : "+v"(num1[r]) : "v"(tp[t + 1]), "v"(wq));
                asm("v_dot2_f32_f16 %0, %1, %2, %0"
                    : "+v"(den0[r]) : "v"(tp[t]),     "v"(wd));
                asm("v_dot2_f32_f16 %0, %1, %2, %0"
                    : "+v"(den1[r]) : "v"(tp[t + 1]), "v"(wd));
            }
        }
    }
#pragma unroll
    for (int r = 0; r < 7; ++r) {
        o0[r] = num0[r] * __builtin_amdgcn_rcpf(den0[r]);
        o1[r] = num1[r] * __builtin_amdgcn_rcpf(den1[r]);
    }
}

__device__ __forceinline__ float sigmoidf_(float s) {
    return __builtin_amdgcn_rcpf(1.f + __expf(-s));
}

// ---------------------------------------------------------------------------
// FULLY FUSED, 8 waves/block, ONE BRANCH PER WAVE, one block per image
// (r13/r17 structure). LDS ~43.6 KB (2 blocks/CU still fits: 87 KB < 160 KB).
// __launch_bounds__(512,2): 2nd arg is min BLOCKS per CU -> VGPR cap 128
// (r12 lesson: (512,4) -> cap 64 -> 2.7 GB scratch spills).
// ---------------------------------------------------------------------------
__global__ __launch_bounds__(512, 2) void smorph_net_kernel(
    const float* __restrict__ x,       // [512,784]
    const float* __restrict__ sw,      // [8,2,49]
    const float* __restrict__ sa,      // [8,2]
    const float* __restrict__ W1, const float* __restrict__ b1,
    const float* __restrict__ W2, const float* __restrict__ b2,
    const float* __restrict__ W3, const float* __restrict__ b3,
    float* __restrict__ out)           // [512,10]
{
    __shared__ __align__(16) unsigned bufs[8][IMG_U];    // 36,992 B
    __shared__ __align__(16) uint2    wtab[8][2][52];    //  6,656 B

    const int b    = blockIdx.x;       // 512 blocks
    const int tid  = threadIdx.x;      // 0..511
    const int f    = tid >> 6;         // wave = branch
    const int lane = tid & 63;

    unsigned* buf = bufs[f];
    const float* src = x + (size_t)b * NPIX;

    const float a1 = sa[f * 2 + 0];
    const float a2 = sa[f * 2 + 1];

    // per-branch packed weight tables (wave-local; program order protects)
    if (lane < 49) {
        union { _Float16 h[2]; unsigned u; } p;
        float w1v = sw[(f * 2 + 0) * 49 + lane];
        float e1  = __expf(a1 * w1v);
        p.h[0] = (_Float16)(w1v * e1);          // lo = qw
        p.h[1] = (_Float16)e1;                  // hi = ew
        wtab[f][0][lane] = make_uint2(p.u, p.u >> 16);   // wd = (ew, 0)
        float w2v = sw[(f * 2 + 1) * 49 + lane];
        float e2  = __expf(a2 * w2v);
        p.h[0] = (_Float16)(w2v * e2);
        p.h[1] = (_Float16)e2;
        wtab[f][1][lane] = make_uint2(p.u, p.u >> 16);
    }

    // phase 0: buf = padded packed (ev,pv); borders (ev=1,pv=0) = 0x00003C00
    for (int idx = lane; idx < IMG_U; idx += 64) {
        int pi = idx / PADW2;
        int pj = idx - pi * PADW2;
        unsigned val = 0x00003C00u;
        if (pi >= 3 && pi < 31 && pj >= 3 && pj < 31) {
            float v = src[(pi - 3) * HW + (pj - 3)];
            float e = __expf(a1 * v);
            union { _Float16 h[2]; unsigned u; } pk;
            pk.h[0] = (_Float16)e;
            pk.h[1] = (_Float16)(v * e);
            val = pk.u;
        }
        buf[idx] = val;
    }

    const bool act = (lane < 56);
    const int s  = lane / 14;          // strip (output rows 7s..7s+6)
    const int c  = lane - s * 14;      // column pair 0..13
    const int R0 = 7 * s;
    const int j2 = 2 * c;

    float o0[7], o1[7];
    if (act) conv2col(buf, wtab[f][0], R0, c, o0, o1);

    // stage-2 packed (ev,pv) overwrite interior in place (own-wave reads done)
    if (act) {
#pragma unroll
        for (int r = 0; r < 7; ++r) {
            union { _Float16 h[2]; unsigned u; } pk;
            float e0 = __expf(a2 * o0[r]);
            pk.h[0] = (_Float16)e0; pk.h[1] = (_Float16)(o0[r] * e0);
            buf[(R0 + r + 3) * PADW2 + (j2 + 3)] = pk.u;
            float e1 = __expf(a2 * o1[r]);
            pk.h[0] = (_Float16)e1; pk.h[1] = (_Float16)(o1[r] * e1);
            buf[(R0 + r + 3) * PADW2 + (j2 + 4)] = pk.u;
        }
    }

    if (act) conv2col(buf, wtab[f][1], R0, c, o0, o1);

    // dense 28x28 f32 plane aliased over own buf (3136 B <= 4624 B)
    float* outp = (float*)buf;
    if (act) {
#pragma unroll
        for (int r = 0; r < 7; ++r) {
            outp[(R0 + r) * HW + j2]     = o0[r];
            outp[(R0 + r) * HW + j2 + 1] = o1[r];
        }
    }

    // 4x4 mean pool -> REGISTER (feat write must wait: it aliases wtab)
    float poolsum = 0.f;
    if (lane < 49) {
        int pi = lane / 7;
        int pj = lane - pi * 7;
#pragma unroll
        for (int di = 0; di < 4; ++di)
#pragma unroll
            for (int dj = 0; dj < 4; ++dj)
                poolsum += outp[(pi * 4 + di) * HW + (pj * 4 + dj)];
        poolsum *= 0.0625f;
    }
    __syncthreads();                    // all convs done; wtab now dead

    // feat/h1/h2 alias the wtab region (2,384 B needed, 6,656 available)
    float* feat = (float*)&wtab[0][0][0];
    float* h1   = feat + 392;           // offset 1568 B (16B mult)
    float* h2   = h1 + 120;             // offset 2048 B (16B mult)

    if (lane < 49) feat[f * 49 + lane] = poolsum;
    __syncthreads();

    // ---- inline MLP (4 lanes per neuron) ----
    if (tid < 480) {
        int n = tid >> 2, h = tid & 3;
        const float4* wr = (const float4*)(W1 + n * 392);
        const float4* fv = (const float4*)feat;
        float c0 = 0.f, c1 = 0.f, c2 = 0.f, c3 = 0.f;
        for (int k = h; k < 98; k += 4) {
            float4 w = wr[k];
            float4 v = fv[k];
            c0 = fmaf(w.x, v.x, c0);
            c1 = fmaf(w.y, v.y, c1);
            c2 = fmaf(w.z, v.z, c2);
            c3 = fmaf(w.w, v.w, c3);
        }
        float acc = (c0 + c1) + (c2 + c3);
        acc += __shfl_xor(acc, 1);
        acc += __shfl_xor(acc, 2);
        if (h == 0) h1[n] = sigmoidf_(acc + b1[n]);
    }
    __syncthreads();

    if (tid < 336) {
        int n = tid >> 2, h = tid & 3;
        const float4* wr = (const float4*)(W2 + n * 120);
        const float4* hv = (const float4*)h1;
        float c0 = 0.f, c1 = 0.f, c2 = 0.f, c3 = 0.f;
        for (int k = h; k < 30; k += 4) {
            float4 w = wr[k];
            float4 v = hv[k];
            c0 = fmaf(w.x, v.x, c0);
            c1 = fmaf(w.y, v.y, c1);
            c2 = fmaf(w.z, v.z, c2);
            c3 = fmaf(w.w, v.w, c3);
        }
        float acc = (c0 + c1) + (c2 + c3);
        acc += __shfl_xor(acc, 1);
        acc += __shfl_xor(acc, 2);
        if (h == 0) h2[n] = sigmoidf_(acc + b2[n]);
    }
    __syncthreads();

    if (tid < 40) {
        int n = tid >> 2, q = tid & 3;
        const float4* wr = (const float4*)(W3 + n * 84);
        const float4* hv = (const float4*)h2;
        float c0 = 0.f, c1 = 0.f, c2 = 0.f, c3 = 0.f;
        for (int k = q; k < 21; k += 4) {
            float4 w = wr[k];
            float4 v = hv[k];
            c0 = fmaf(w.x, v.x, c0);
            c1 = fmaf(w.y, v.y, c1);
            c2 = fmaf(w.z, v.z, c2);
            c3 = fmaf(w.w, v.w, c3);
        }
        float acc = (c0 + c1) + (c2 + c3);
        acc += __shfl_xor(acc, 1);
        acc += __shfl_xor(acc, 2);
        if (q == 0) out[(size_t)b * 10 + n] = sigmoidf_(acc + b3[n]);
    }
}

extern "C" void kernel_launch(void* const* d_in, const int* in_sizes, int n_in,
                              void* d_out, int out_size, void* d_ws, size_t ws_size,
                              hipStream_t stream) {
    const float* x  = (const float*)d_in[0];
    const float* sw = (const float*)d_in[1];
    const float* sa = (const float*)d_in[2];
    const float* W1 = (const float*)d_in[3];
    const float* b1 = (const float*)d_in[4];
    const float* W2 = (const float*)d_in[5];
    const float* b2 = (const float*)d_in[6];
    const float* W3 = (const float*)d_in[7];
    const float* b3 = (const float*)d_in[8];
    float* out = (float*)d_out;

    smorph_net_kernel<<<NB, 512, 0, stream>>>(x, sw, sa, W1, b1, W2, b2, W3, b3, out);
}

// Round 2
// 104.425 us; speedup vs baseline: 1.1488x; 1.1488x over previous
//
#include <hip/hip_runtime.h>

#define HW 28
#define NPIX 784
#define NB 512
#define PADW2 34                 // row stride in PIXELS (cols -3..30); 136 B, 8B-aligned rows
#define PADH 34                  // rows -3..30
#define IMG_U (PADH * PADW2)     // 1156 packed pixels = 4624 B per branch buffer

// ---------------------------------------------------------------------------
// 7x2 output tile per thread. Image pixels packed fp16x2 (ev lo, pv hi) in
// one uint. Weights are WAVE-UNIFORM -> live in SGPRs via v_readlane
// broadcast (r18 lesson: LDS weight re-fetch per tap was the critical path;
// r17 lesson: fma_mix is half-rate). Per tap-output now:
//   num += v_dot2_f32_f16(tap, s_wq)        ( = ev*qw + pv*ew, FULL rate )
//   den += v_dot2_f32_f16(tap, s_wd)        ( = ev*ew + pv*0,  FULL rate )
// with s_wd = s_lshr_b32(s_wq,16) on the SCALAR pipe (co-issues, ~free).
// 4 cyc/tap-output, zero in-loop LDS traffic.
// ---------------------------------------------------------------------------
__device__ __forceinline__ void conv2col(const unsigned* sbuf,
                                         unsigned wpack,  // lane i<49 holds packed (qw,ew)
                                         int R0, int c, float o0[7], float o1[7])
{
    // broadcast the 49 wave-uniform weights into SGPRs
    unsigned Wq[49];
#pragma unroll
    for (int i = 0; i < 49; ++i)
        Wq[i] = __builtin_amdgcn_readlane(wpack, i);

    float num0[7], num1[7], den0[7], den1[7];
#pragma unroll
    for (int r = 0; r < 7; ++r) {
        num0[r] = 0.f; num1[r] = 0.f; den0[r] = 0.f; den1[r] = 0.f;
    }

#pragma unroll
    for (int rr = 0; rr < 13; ++rr) {
        const uint2* rq = (const uint2*)(sbuf + (R0 + rr) * PADW2 + 2 * c); // 8B-aligned
        uint2 a0 = rq[0], a1 = rq[1], a2 = rq[2], a3 = rq[3];
        unsigned tp[8] = {a0.x, a0.y, a1.x, a1.y, a2.x, a2.y, a3.x, a3.y};
#pragma unroll
        for (int r = 0; r < 7; ++r) {
            if (r > rr || rr - r > 6) continue;     // compile-time fold
            const int di = rr - r;
#pragma unroll
            for (int t = 0; t < 7; ++t) {
                unsigned wq = Wq[di * 7 + t];
                unsigned wd;
                asm("s_lshr_b32 %0, %1, 16" : "=s"(wd) : "s"(wq));  // (ew, 0)
                asm("v_dot2_f32_f16 %0, %1, %2, %0"
                    : "+v"(num0[r]) : "v"(tp[t]),     "s"(wq));
                asm("v_dot2_f32_f16 %0, %1, %2, %0"
                    : "+v"(num1[r]) : "v"(tp[t + 1]), "s"(wq));
                asm("v_dot2_f32_f16 %0, %1, %2, %0"
                    : "+v"(den0[r]) : "v"(tp[t]),     "s"(wd));
                asm("v_dot2_f32_f16 %0, %1, %2, %0"
                    : "+v"(den1[r]) : "v"(tp[t + 1]), "s"(wd));
            }
        }
    }
#pragma unroll
    for (int r = 0; r < 7; ++r) {
        o0[r] = num0[r] * __builtin_amdgcn_rcpf(den0[r]);
        o1[r] = num1[r] * __builtin_amdgcn_rcpf(den1[r]);
    }
}

__device__ __forceinline__ float sigmoidf_(float s) {
    return __builtin_amdgcn_rcpf(1.f + __expf(-s));
}

// ---------------------------------------------------------------------------
// FULLY FUSED, 8 waves/block, ONE BRANCH PER WAVE, one block per image
// (r13/r17 structure). LDS ~39.5 KB. __launch_bounds__(512,2): 2nd arg is
// min BLOCKS per CU -> VGPR cap 128 (r12 lesson: (512,4) -> cap 64 -> 2.7 GB
// scratch spills).
// ---------------------------------------------------------------------------
__global__ __launch_bounds__(512, 2) void smorph_net_kernel(
    const float* __restrict__ x,       // [512,784]
    const float* __restrict__ sw,      // [8,2,49]
    const float* __restrict__ sa,      // [8,2]
    const float* __restrict__ W1, const float* __restrict__ b1,
    const float* __restrict__ W2, const float* __restrict__ b2,
    const float* __restrict__ W3, const float* __restrict__ b3,
    float* __restrict__ out)           // [512,10]
{
    __shared__ __align__(16) unsigned bufs[8][IMG_U];      // 36,992 B
    __shared__ __align__(16) float    mlp[392 + 120 + 128]; // 2,560 B (feat|h1|h2)

    const int b    = blockIdx.x;       // 512 blocks
    const int tid  = threadIdx.x;      // 0..511
    const int f    = tid >> 6;         // wave = branch
    const int lane = tid & 63;

    unsigned* buf = bufs[f];
    const float* src = x + (size_t)b * NPIX;

    const float a1 = sa[f * 2 + 0];
    const float a2 = sa[f * 2 + 1];

    // per-branch packed weights: lane i<49 holds (qw=w*ew, ew) for its tap.
    // Stays in VGPRs; conv2col broadcasts to SGPRs via readlane.
    unsigned wp1 = 0, wp2 = 0;
    if (lane < 49) {
        union { _Float16 h[2]; unsigned u; } p;
        float w1v = sw[(f * 2 + 0) * 49 + lane];
        float e1  = __expf(a1 * w1v);
        p.h[0] = (_Float16)(w1v * e1);          // lo = qw
        p.h[1] = (_Float16)e1;                  // hi = ew
        wp1 = p.u;
        float w2v = sw[(f * 2 + 1) * 49 + lane];
        float e2  = __expf(a2 * w2v);
        p.h[0] = (_Float16)(w2v * e2);
        p.h[1] = (_Float16)e2;
        wp2 = p.u;
    }

    // phase 0: buf = padded packed (ev,pv); borders (ev=1,pv=0) = 0x00003C00
    for (int idx = lane; idx < IMG_U; idx += 64) {
        int pi = idx / PADW2;
        int pj = idx - pi * PADW2;
        unsigned val = 0x00003C00u;
        if (pi >= 3 && pi < 31 && pj >= 3 && pj < 31) {
            float v = src[(pi - 3) * HW + (pj - 3)];
            float e = __expf(a1 * v);
            union { _Float16 h[2]; unsigned u; } pk;
            pk.h[0] = (_Float16)e;
            pk.h[1] = (_Float16)(v * e);
            val = pk.u;
        }
        buf[idx] = val;
    }

    const bool act = (lane < 56);
    const int s  = lane / 14;          // strip (output rows 7s..7s+6)
    const int c  = lane - s * 14;      // column pair 0..13
    const int R0 = 7 * s;
    const int j2 = 2 * c;

    float o0[7], o1[7];
    if (act) conv2col(buf, wp1, R0, c, o0, o1);

    // stage-2 packed (ev,pv) overwrite interior in place (own-wave reads done)
    if (act) {
#pragma unroll
        for (int r = 0; r < 7; ++r) {
            union { _Float16 h[2]; unsigned u; } pk;
            float e0 = __expf(a2 * o0[r]);
            pk.h[0] = (_Float16)e0; pk.h[1] = (_Float16)(o0[r] * e0);
            buf[(R0 + r + 3) * PADW2 + (j2 + 3)] = pk.u;
            float e1 = __expf(a2 * o1[r]);
            pk.h[0] = (_Float16)e1; pk.h[1] = (_Float16)(o1[r] * e1);
            buf[(R0 + r + 3) * PADW2 + (j2 + 4)] = pk.u;
        }
    }

    if (act) conv2col(buf, wp2, R0, c, o0, o1);

    // dense 28x28 f32 plane aliased over own buf (3136 B <= 4624 B)
    float* outp = (float*)buf;
    if (act) {
#pragma unroll
        for (int r = 0; r < 7; ++r) {
            outp[(R0 + r) * HW + j2]     = o0[r];
            outp[(R0 + r) * HW + j2 + 1] = o1[r];
        }
    }

    // 4x4 mean pool -> feat (separate LDS buffer, no aliasing hazard)
    float* feat = mlp;
    float* h1   = mlp + 392;
    float* h2   = mlp + 512;

    if (lane < 49) {
        int pi = lane / 7;
        int pj = lane - pi * 7;
        float poolsum = 0.f;
#pragma unroll
        for (int di = 0; di < 4; ++di)
#pragma unroll
            for (int dj = 0; dj < 4; ++dj)
                poolsum += outp[(pi * 4 + di) * HW + (pj * 4 + dj)];
        feat[f * 49 + lane] = poolsum * 0.0625f;
    }
    __syncthreads();

    // ---- inline MLP (4 lanes per neuron) ----
    if (tid < 480) {
        int n = tid >> 2, h = tid & 3;
        const float4* wr = (const float4*)(W1 + n * 392);
        const float4* fv = (const float4*)feat;
        float c0 = 0.f, c1 = 0.f, c2 = 0.f, c3 = 0.f;
        for (int k = h; k < 98; k += 4) {
            float4 w = wr[k];
            float4 v = fv[k];
            c0 = fmaf(w.x, v.x, c0);
            c1 = fmaf(w.y, v.y, c1);
            c2 = fmaf(w.z, v.z, c2);
            c3 = fmaf(w.w, v.w, c3);
        }
        float acc = (c0 + c1) + (c2 + c3);
        acc += __shfl_xor(acc, 1);
        acc += __shfl_xor(acc, 2);
        if (h == 0) h1[n] = sigmoidf_(acc + b1[n]);
    }
    __syncthreads();

    if (tid < 336) {
        int n = tid >> 2, h = tid & 3;
        const float4* wr = (const float4*)(W2 + n * 120);
        const float4* hv = (const float4*)h1;
        float c0 = 0.f, c1 = 0.f, c2 = 0.f, c3 = 0.f;
        for (int k = h; k < 30; k += 4) {
            float4 w = wr[k];
            float4 v = hv[k];
            c0 = fmaf(w.x, v.x, c0);
            c1 = fmaf(w.y, v.y, c1);
            c2 = fmaf(w.z, v.z, c2);
            c3 = fmaf(w.w, v.w, c3);
        }
        float acc = (c0 + c1) + (c2 + c3);
        acc += __shfl_xor(acc, 1);
        acc += __shfl_xor(acc, 2);
        if (h == 0) h2[n] = sigmoidf_(acc + b2[n]);
    }
    __syncthreads();

    if (tid < 40) {
        int n = tid >> 2, q = tid & 3;
        const float4* wr = (const float4*)(W3 + n * 84);
        const float4* hv = (const float4*)h2;
        float c0 = 0.f, c1 = 0.f, c2 = 0.f, c3 = 0.f;
        for (int k = q; k < 21; k += 4) {
            float4 w = wr[k];
            float4 v = hv[k];
            c0 = fmaf(w.x, v.x, c0);
            c1 = fmaf(w.y, v.y, c1);
            c2 = fmaf(w.z, v.z, c2);
            c3 = fmaf(w.w, v.w, c3);
        }
        float acc = (c0 + c1) + (c2 + c3);
        acc += __shfl_xor(acc, 1);
        acc += __shfl_xor(acc, 2);
        if (q == 0) out[(size_t)b * 10 + n] = sigmoidf_(acc + b3[n]);
    }
}

extern "C" void kernel_launch(void* const* d_in, const int* in_sizes, int n_in,
                              void* d_out, int out_size, void* d_ws, size_t ws_size,
                              hipStream_t stream) {
    const float* x  = (const float*)d_in[0];
    const float* sw = (const float*)d_in[1];
    const float* sa = (const float*)d_in[2];
    const float* W1 = (const float*)d_in[3];
    const float* b1 = (const float*)d_in[4];
    const float* W2 = (const float*)d_in[5];
    const float* b2 = (const float*)d_in[6];
    const float* W3 = (const float*)d_in[7];
    const float* b3 = (const float*)d_in[8];
    float* out = (float*)d_out;

    smorph_net_kernel<<<NB, 512, 0, stream>>>(x, sw, sa, W1, b1, W2, b2, W3, b3, out);
}

// Round 3
// 101.117 us; speedup vs baseline: 1.1864x; 1.0327x over previous
//
#include <hip/hip_runtime.h>

#define HW 28
#define NPIX 784
#define NB 512
#define PADW2 34                 // row stride in PIXELS (cols -3..30); 136 B, 8B-aligned rows
#define PADH 34                  // rows -3..30
#define IMG_U (PADH * PADW2)     // 1156 packed pixels = 4624 B per branch buffer

// ---------------------------------------------------------------------------
// 7x2 output tile per thread. Image pixels packed fp16x2 (ev lo, pv hi) in
// one uint. Weights are WAVE-UNIFORM -> SGPRs via v_readlane (r19: zero
// in-loop LDS weight traffic; den dot2 against (ew,0) full rate).
// r19 lesson: VGPR_Count==36 == 8 taps + 28 accs -> compiler did ZERO tap
// prefetch; each row-step stalled ~120cy on lgkmcnt with 4 lockstep waves
// stalling together. This version software-pipelines the tap reads by one
// row (ping-pong regs + sched_barrier to pin the issue order).
// ---------------------------------------------------------------------------
__device__ __forceinline__ void conv2col(const unsigned* sbuf,
                                         unsigned wpack,  // lane i<49 holds packed (qw,ew)
                                         int R0, int c, float o0[7], float o1[7])
{
    // issue row-0 tap loads FIRST; the 49 readlanes below cover their latency
    const uint2* rq0 = (const uint2*)(sbuf + R0 * PADW2 + 2 * c);  // 8B-aligned
    uint2 p0 = rq0[0], p1 = rq0[1], p2 = rq0[2], p3 = rq0[3];

    // broadcast the 49 wave-uniform weights into SGPRs
    unsigned Wq[49];
#pragma unroll
    for (int i = 0; i < 49; ++i)
        Wq[i] = __builtin_amdgcn_readlane(wpack, i);

    float num0[7], num1[7], den0[7], den1[7];
#pragma unroll
    for (int r = 0; r < 7; ++r) {
        num0[r] = 0.f; num1[r] = 0.f; den0[r] = 0.f; den1[r] = 0.f;
    }

#pragma unroll
    for (int rr = 0; rr < 13; ++rr) {
        // prefetch next row's taps before computing this row
        uint2 n0, n1, n2, n3;
        if (rr < 12) {
            const uint2* rq = (const uint2*)(sbuf + (R0 + rr + 1) * PADW2 + 2 * c);
            n0 = rq[0]; n1 = rq[1]; n2 = rq[2]; n3 = rq[3];
            __builtin_amdgcn_sched_barrier(0);   // pin: loads stay above compute
        }
        unsigned tp[8] = {p0.x, p0.y, p1.x, p1.y, p2.x, p2.y, p3.x, p3.y};
#pragma unroll
        for (int r = 0; r < 7; ++r) {
            if (r > rr || rr - r > 6) continue;     // compile-time fold
            const int di = rr - r;
#pragma unroll
            for (int t = 0; t < 7; ++t) {
                unsigned wq = Wq[di * 7 + t];
                unsigned wd;
                asm("s_lshr_b32 %0, %1, 16" : "=s"(wd) : "s"(wq));  // (ew, 0)
                asm("v_dot2_f32_f16 %0, %1, %2, %0"
                    : "+v"(num0[r]) : "v"(tp[t]),     "s"(wq));
                asm("v_dot2_f32_f16 %0, %1, %2, %0"
                    : "+v"(num1[r]) : "v"(tp[t + 1]), "s"(wq));
                asm("v_dot2_f32_f16 %0, %1, %2, %0"
                    : "+v"(den0[r]) : "v"(tp[t]),     "s"(wd));
                asm("v_dot2_f32_f16 %0, %1, %2, %0"
                    : "+v"(den1[r]) : "v"(tp[t + 1]), "s"(wd));
            }
        }
        if (rr < 12) { p0 = n0; p1 = n1; p2 = n2; p3 = n3; }
    }
#pragma unroll
    for (int r = 0; r < 7; ++r) {
        o0[r] = num0[r] * __builtin_amdgcn_rcpf(den0[r]);
        o1[r] = num1[r] * __builtin_amdgcn_rcpf(den1[r]);
    }
}

__device__ __forceinline__ float sigmoidf_(float s) {
    return __builtin_amdgcn_rcpf(1.f + __expf(-s));
}

// ---------------------------------------------------------------------------
// FULLY FUSED, 8 waves/block, ONE BRANCH PER WAVE, one block per image
// (r13/r17 structure). LDS ~38.6 KB. __launch_bounds__(512,2): 2nd arg is
// min BLOCKS per CU -> VGPR cap 128 (r12 lesson: (512,4) -> cap 64 -> 2.7 GB
// scratch spills).
// ---------------------------------------------------------------------------
__global__ __launch_bounds__(512, 2) void smorph_net_kernel(
    const float* __restrict__ x,       // [512,784]
    const float* __restrict__ sw,      // [8,2,49]
    const float* __restrict__ sa,      // [8,2]
    const float* __restrict__ W1, const float* __restrict__ b1,
    const float* __restrict__ W2, const float* __restrict__ b2,
    const float* __restrict__ W3, const float* __restrict__ b3,
    float* __restrict__ out)           // [512,10]
{
    __shared__ __align__(16) unsigned bufs[8][IMG_U];      // 36,992 B
    __shared__ __align__(16) float    mlp[392 + 120 + 128]; // 2,560 B (feat|h1|h2)

    const int b    = blockIdx.x;       // 512 blocks
    const int tid  = threadIdx.x;      // 0..511
    const int f    = tid >> 6;         // wave = branch
    const int lane = tid & 63;

    unsigned* buf = bufs[f];
    const float* src = x + (size_t)b * NPIX;

    const float a1 = sa[f * 2 + 0];
    const float a2 = sa[f * 2 + 1];

    // per-branch packed weights: lane i<49 holds (qw=w*ew, ew) for its tap.
    // Stays in VGPRs; conv2col broadcasts to SGPRs via readlane.
    unsigned wp1 = 0, wp2 = 0;
    if (lane < 49) {
        union { _Float16 h[2]; unsigned u; } p;
        float w1v = sw[(f * 2 + 0) * 49 + lane];
        float e1  = __expf(a1 * w1v);
        p.h[0] = (_Float16)(w1v * e1);          // lo = qw
        p.h[1] = (_Float16)e1;                  // hi = ew
        wp1 = p.u;
        float w2v = sw[(f * 2 + 1) * 49 + lane];
        float e2  = __expf(a2 * w2v);
        p.h[0] = (_Float16)(w2v * e2);
        p.h[1] = (_Float16)e2;
        wp2 = p.u;
    }

    // phase 0a: fill whole padded buffer with border constant (ev=1, pv=0)
    for (int idx = lane; idx < IMG_U; idx += 64)
        buf[idx] = 0x00003C00u;

    // phase 0b: interior — 13 fully-unrolled INDEPENDENT loads per lane so
    // all global loads issue up front (one latency, not 19 chained)
#pragma unroll
    for (int k = 0; k < 13; ++k) {
        int p = lane + 64 * k;
        if (p < NPIX) {
            float v = src[p];
            int pi = p / HW;
            int pj = p - pi * HW;
            float e = __expf(a1 * v);
            union { _Float16 h[2]; unsigned u; } pk;
            pk.h[0] = (_Float16)e;
            pk.h[1] = (_Float16)(v * e);
            buf[(pi + 3) * PADW2 + (pj + 3)] = pk.u;
        }
    }

    const bool act = (lane < 56);
    const int s  = lane / 14;          // strip (output rows 7s..7s+6)
    const int c  = lane - s * 14;      // column pair 0..13
    const int R0 = 7 * s;
    const int j2 = 2 * c;

    float o0[7], o1[7];
    if (act) conv2col(buf, wp1, R0, c, o0, o1);

    // stage-2 packed (ev,pv) overwrite interior in place (own-wave reads done)
    if (act) {
#pragma unroll
        for (int r = 0; r < 7; ++r) {
            union { _Float16 h[2]; unsigned u; } pk;
            float e0 = __expf(a2 * o0[r]);
            pk.h[0] = (_Float16)e0; pk.h[1] = (_Float16)(o0[r] * e0);
            buf[(R0 + r + 3) * PADW2 + (j2 + 3)] = pk.u;
            float e1 = __expf(a2 * o1[r]);
            pk.h[0] = (_Float16)e1; pk.h[1] = (_Float16)(o1[r] * e1);
            buf[(R0 + r + 3) * PADW2 + (j2 + 4)] = pk.u;
        }
    }

    if (act) conv2col(buf, wp2, R0, c, o0, o1);

    // dense 28x28 f32 plane aliased over own buf (3136 B <= 4624 B)
    float* outp = (float*)buf;
    if (act) {
#pragma unroll
        for (int r = 0; r < 7; ++r) {
            outp[(R0 + r) * HW + j2]     = o0[r];
            outp[(R0 + r) * HW + j2 + 1] = o1[r];
        }
    }

    // 4x4 mean pool -> feat (separate LDS buffer, no aliasing hazard)
    float* feat = mlp;
    float* h1   = mlp + 392;
    float* h2   = mlp + 512;

    if (lane < 49) {
        int pi = lane / 7;
        int pj = lane - pi * 7;
        float poolsum = 0.f;
#pragma unroll
        for (int di = 0; di < 4; ++di)
#pragma unroll
            for (int dj = 0; dj < 4; ++dj)
                poolsum += outp[(pi * 4 + di) * HW + (pj * 4 + dj)];
        feat[f * 49 + lane] = poolsum * 0.0625f;
    }
    __syncthreads();

    // ---- inline MLP (4 lanes per neuron) ----
    if (tid < 480) {
        int n = tid >> 2, h = tid & 3;
        const float4* wr = (const float4*)(W1 + n * 392);
        const float4* fv = (const float4*)feat;
        float c0 = 0.f, c1 = 0.f, c2 = 0.f, c3 = 0.f;
        for (int k = h; k < 98; k += 4) {
            float4 w = wr[k];
            float4 v = fv[k];
            c0 = fmaf(w.x, v.x, c0);
            c1 = fmaf(w.y, v.y, c1);
            c2 = fmaf(w.z, v.z, c2);
            c3 = fmaf(w.w, v.w, c3);
        }
        float acc = (c0 + c1) + (c2 + c3);
        acc += __shfl_xor(acc, 1);
        acc += __shfl_xor(acc, 2);
        if (h == 0) h1[n] = sigmoidf_(acc + b1[n]);
    }
    __syncthreads();

    if (tid < 336) {
        int n = tid >> 2, h = tid & 3;
        const float4* wr = (const float4*)(W2 + n * 120);
        const float4* hv = (const float4*)h1;
        float c0 = 0.f, c1 = 0.f, c2 = 0.f, c3 = 0.f;
        for (int k = h; k < 30; k += 4) {
            float4 w = wr[k];
            float4 v = hv[k];
            c0 = fmaf(w.x, v.x, c0);
            c1 = fmaf(w.y, v.y, c1);
            c2 = fmaf(w.z, v.z, c2);
            c3 = fmaf(w.w, v.w, c3);
        }
        float acc = (c0 + c1) + (c2 + c3);
        acc += __shfl_xor(acc, 1);
        acc += __shfl_xor(acc, 2);
        if (h == 0) h2[n] = sigmoidf_(acc + b2[n]);
    }
    __syncthreads();

    if (tid < 40) {
        int n = tid >> 2, q = tid & 3;
        const float4* wr = (const float4*)(W3 + n * 84);
        const float4* hv = (const float4*)h2;
        float c0 = 0.f, c1 = 0.f, c2 = 0.f, c3 = 0.f;
        for (int k = q; k < 21; k += 4) {
            float4 w = wr[k];
            float4 v = hv[k];
            c0 = fmaf(w.x, v.x, c0);
            c1 = fmaf(w.y, v.y, c1);
            c2 = fmaf(w.z, v.z, c2);
            c3 = fmaf(w.w, v.w, c3);
        }
        float acc = (c0 + c1) + (c2 + c3);
        acc += __shfl_xor(acc, 1);
        acc += __shfl_xor(acc, 2);
        if (q == 0) out[(size_t)b * 10 + n] = sigmoidf_(acc + b3[n]);
    }
}

extern "C" void kernel_launch(void* const* d_in, const int* in_sizes, int n_in,
                              void* d_out, int out_size, void* d_ws, size_t ws_size,
                              hipStream_t stream) {
    const float* x  = (const float*)d_in[0];
    const float* sw = (const float*)d_in[1];
    const float* sa = (const float*)d_in[2];
    const float* W1 = (const float*)d_in[3];
    const float* b1 = (const float*)d_in[4];
    const float* W2 = (const float*)d_in[5];
    const float* b2 = (const float*)d_in[6];
    const float* W3 = (const float*)d_in[7];
    const float* b3 = (const float*)d_in[8];
    float* out = (float*)d_out;

    smorph_net_kernel<<<NB, 512, 0, stream>>>(x, sw, sa, W1, b1, W2, b2, W3, b3, out);
}